// Round 3
// baseline (306.079 us; speedup 1.0000x reference)
//
#include <hip/hip_runtime.h>
#include <stdint.h>

typedef unsigned short u16;
typedef unsigned char u8;
typedef __attribute__((ext_vector_type(8))) short short8;
typedef __attribute__((ext_vector_type(4))) float f32x4;
typedef __attribute__((ext_vector_type(16))) float f32x16;
typedef __attribute__((ext_vector_type(4))) int i32x4;
typedef __attribute__((ext_vector_type(8))) int i32x8;

#define BATCH 16384L
#define WSCALE 64.0f
#define INV_WSCALE (1.0f / 64.0f)
#define SCALE_ONE 0x7f7f7f7f   // e8m0 biased exp 127 = 1.0 in all 4 bytes
#define INVB (1.0f / 16384.0f)

__device__ __forceinline__ u16 f2bf_trunc(float f) {
    union { float f; uint32_t u; } cv; cv.f = f;
    return (u16)(cv.u >> 16);
}
__device__ __forceinline__ float bf2f(u16 h) {
    union { uint32_t u; float f; } cv; cv.u = ((uint32_t)h) << 16;
    return cv.f;
}
template<bool HI>
__device__ __forceinline__ uint32_t fp8pk(float a, float b, uint32_t old) {
    return (uint32_t)__builtin_amdgcn_cvt_pk_fp8_f32(a, b, (int)old, HI);
}
__device__ __forceinline__ u8 f2fp8(float v) {
    return (u8)(__builtin_amdgcn_cvt_pk_fp8_f32(v, v, 0, false) & 0xff);
}

// ---------------------------------------------------------------------------
// Kernel 1: per-batch gram pairs (truncating hi/lo split bf16 MFMA ~ fp32)
//           + emit fp8 copy of x for GEMM1 (reads x exactly once)
//           + block 0 zeroes the BN-stats accumulators (replaces memset)
//           + blocks >= 4096: W1 fp32->fp8 transpose
// ---------------------------------------------------------------------------
__global__ __launch_bounds__(256) void k_gram(const float* __restrict__ x,
                                              const float* __restrict__ Wc,
                                              const float* __restrict__ W1,
                                              u8* __restrict__ xb,
                                              u8* __restrict__ w1f,
                                              float* __restrict__ spair,
                                              float* __restrict__ stats) {
    if (blockIdx.x >= 4096) {
        // W1 (2048x1024) -> w1f (1024x2048) fp8, scale 64
        __shared__ float tile[32][33];
        const int bid2 = blockIdx.x - 4096;           // 0..2047
        const int nb = (bid2 & 31) * 32;              // over N=1024
        const int kb = (bid2 >> 5) * 32;              // over K=2048
        const int tx = threadIdx.x & 31, ty = threadIdx.x >> 5;
        for (int r = ty; r < 32; r += 8)
            tile[r][tx] = W1[(long)(kb + r) * 1024 + nb + tx];
        __syncthreads();
        for (int r = ty; r < 32; r += 8)
            w1f[(long)(nb + r) * 2048 + kb + tx] = f2fp8(WSCALE * tile[tx][r]);
        return;
    }
    if (blockIdx.x == 0) {
        for (int j = threadIdx.x; j < 3072; j += 256) stats[j] = 0.f;
    }
    const int wave = threadIdx.x >> 6;
    const int lane = threadIdx.x & 63;
    const long b = (long)blockIdx.x * 4 + wave;
    const int r16 = lane & 15, quad = lane >> 4;
    const float* xg = x + b * 2048;

    short8 hi[2][2], lo[2][2];
    for (int mt = 0; mt < 2; mt++) {
        for (int k0 = 0; k0 < 2; k0++) {
            const int row = mt * 16 + r16;
            const int kof = k0 * 32 + quad * 8;
            const float* p = xg + row * 64 + kof;
            float4 p0 = *(const float4*)p;
            float4 p1 = *(const float4*)(p + 4);
            float v[8] = {p0.x, p0.y, p0.z, p0.w, p1.x, p1.y, p1.z, p1.w};
            short8 h, l;
            for (int j = 0; j < 8; j++) {
                u16 hb = f2bf_trunc(v[j]);          // truncate: lo absorbs the error
                h[j] = (short)hb;
                l[j] = (short)f2bf_trunc(v[j] - bf2f(hb));
            }
            hi[mt][k0] = h; lo[mt][k0] = l;
            uint32_t w0 = fp8pk<false>(v[0], v[1], 0); w0 = fp8pk<true>(v[2], v[3], w0);
            uint32_t w1 = fp8pk<false>(v[4], v[5], 0); w1 = fp8pk<true>(v[6], v[7], w1);
            *(uint2*)(xb + b * 2048 + row * 64 + kof) = make_uint2(w0, w1);
        }
    }
    f32x4 zero = {0.f, 0.f, 0.f, 0.f};
    f32x4 acc[2][2];
    for (int mt = 0; mt < 2; mt++) for (int nt = 0; nt < 2; nt++) acc[mt][nt] = zero;
    for (int k0 = 0; k0 < 2; k0++)
        for (int mt = 0; mt < 2; mt++)
            for (int nt = 0; nt < 2; nt++) {
                acc[mt][nt] = __builtin_amdgcn_mfma_f32_16x16x32_bf16(hi[mt][k0], hi[nt][k0], acc[mt][nt], 0, 0, 0);
                acc[mt][nt] = __builtin_amdgcn_mfma_f32_16x16x32_bf16(hi[mt][k0], lo[nt][k0], acc[mt][nt], 0, 0, 0);
                acc[mt][nt] = __builtin_amdgcn_mfma_f32_16x16x32_bf16(lo[mt][k0], hi[nt][k0], acc[mt][nt], 0, 0, 0);
            }
    float pacc = 0.f;
    for (int mt = 0; mt < 2; mt++)
        for (int nt = 0; nt < 2; nt++)
            for (int r = 0; r < 4; r++) {
                int row = mt * 16 + quad * 4 + r;
                int col = nt * 16 + r16;
                if (col > row) {
                    int p = 31 * row - (row * (row - 1)) / 2 + (col - row - 1);
                    pacc += acc[mt][nt][r] * Wc[64 + p];
                }
            }
    for (int off = 1; off < 64; off <<= 1) pacc += __shfl_xor(pacc, off);
    if (lane == 0) spair[b] = pacc;
}

// ---------------------------------------------------------------------------
// 32B fragment from XOR-swizzled 64B LDS row (BK=64: 4 chunks of 16B per row;
// swizzle s = (r&3)^((r>>2)&3), matching the pre-swizzled global source)
// ---------------------------------------------------------------------------
__device__ __forceinline__ i32x8 frag64(const u8* __restrict__ lds, int R, int cb) {
    const int s = (R & 3) ^ ((R >> 2) & 3);
    i32x4 lo = *(const i32x4*)&lds[R * 64 + ((cb ^ s) * 16)];
    i32x4 hi = *(const i32x4*)&lds[R * 64 + (((cb + 1) ^ s) * 16)];
    i32x8 r;
    r[0] = lo[0]; r[1] = lo[1]; r[2] = lo[2]; r[3] = lo[3];
    r[4] = hi[0]; r[5] = hi[1]; r[6] = hi[2]; r[7] = hi[3];
    return r;
}

// ---------------------------------------------------------------------------
// Unified pipelined MX-fp8 GEMM: BM=256, BN=128*NTB, BK=64, triple-buffered
// LDS with counted vmcnt (T4): loads for step t+2 issued during step t, wait
// is vmcnt(2L) -- never 0 in steady state. 256 blocks x 512 threads (8 waves
// as 2M x 4N). Epilogue: relu -> fp8 + per-column sum/sumsq atomics.
//   GEMM1: NTB=2 (N=1024, K=2048);  GEMM2: NTB=1 (N=512, K=1024)
// ---------------------------------------------------------------------------
template<int NTB>
__global__ __launch_bounds__(512) void gemm_pipe(const u8* __restrict__ A,
                                                 const u8* __restrict__ Bt,
                                                 const float* __restrict__ bias,
                                                 u8* __restrict__ C,
                                                 float* __restrict__ sums,
                                                 float* __restrict__ ssq,
                                                 int N, int K, float inv) {
    __shared__ u8 lA[3 * 16384];            // 3 x (256 rows x 64 B)
    __shared__ u8 lB[3 * 8192 * NTB];       // 3 x (128*NTB rows x 64 B)
    const int tid = threadIdx.x;
    const int lane = tid & 63, wave = tid >> 6;
    const int wm = wave >> 2, wn = wave & 3;        // 2M x 4N waves
    const int r32 = lane & 31, hf = lane >> 5;
    const int lid = blockIdx.x;
    const int xcd = lid & 7, t8 = lid >> 3;
    const int nbk = t8 & 3;                          // 4 n-blocks
    const int mbk = xcd * 8 + (t8 >> 2);             // 8 m-bands per XCD
    const long m0 = (long)mbk * 256;
    const long n0 = (long)nbk * (128 * NTB);

    // staging maps: A = 1024 chunks (2/thread), B = 512*NTB chunks (NTB/thread)
    const u8* srcA[2]; int dca[2];
#pragma unroll
    for (int i = 0; i < 2; i++) {
        const int c = tid + 512 * i;                 // 256 rows x 4 chunks
        const int row = c >> 2, pos = c & 3;
        const int g = pos ^ ((row & 3) ^ ((row >> 2) & 3));
        srcA[i] = A + (m0 + row) * (long)K + g * 16;
        dca[i] = c * 16;
    }
    const u8* srcB[NTB]; int dcb[NTB];
#pragma unroll
    for (int i = 0; i < NTB; i++) {
        const int c = tid + 512 * i;                 // 128*NTB rows x 4 chunks
        const int row = c >> 2, pos = c & 3;
        const int g = pos ^ ((row & 3) ^ ((row >> 2) & 3));
        srcB[i] = Bt + (n0 + row) * (long)K + g * 16;
        dcb[i] = c * 16;
    }

    f32x16 acc[4][NTB];
#pragma unroll
    for (int mt = 0; mt < 4; mt++)
#pragma unroll
        for (int nt = 0; nt < NTB; nt++)
#pragma unroll
            for (int r = 0; r < 16; r++) acc[mt][nt][r] = 0.f;

    // prologue: issue K-steps 0 and 1 into buffers 0,1
#pragma unroll
    for (int st = 0; st < 2; st++) {
        const long ko = (long)st << 6;
        u8* da = &lA[st * 16384];
        u8* db = &lB[st * (8192 * NTB)];
#pragma unroll
        for (int i = 0; i < 2; i++)
            __builtin_amdgcn_global_load_lds((const __attribute__((address_space(1))) void*)(srcA[i] + ko),
                                             (__attribute__((address_space(3))) void*)(da + dca[i]), 16, 0, 0);
#pragma unroll
        for (int i = 0; i < NTB; i++)
            __builtin_amdgcn_global_load_lds((const __attribute__((address_space(1))) void*)(srcB[i] + ko),
                                             (__attribute__((address_space(3))) void*)(db + dcb[i]), 16, 0, 0);
    }

    const int NT = K >> 6;
    int rb = 0, wb = 2;
    for (int t = 0; t < NT; ++t) {
        if (t + 2 < NT) {
            // issue loads for step t+2 (buffer wb: its readers finished at the
            // close barrier of step t-1), then counted wait: 2 newer load
            // groups (2L insts) may remain in flight; step-t group is done.
            const long ko = (long)(t + 2) << 6;
            u8* da = &lA[wb * 16384];
            u8* db = &lB[wb * (8192 * NTB)];
#pragma unroll
            for (int i = 0; i < 2; i++)
                __builtin_amdgcn_global_load_lds((const __attribute__((address_space(1))) void*)(srcA[i] + ko),
                                                 (__attribute__((address_space(3))) void*)(da + dca[i]), 16, 0, 0);
#pragma unroll
            for (int i = 0; i < NTB; i++)
                __builtin_amdgcn_global_load_lds((const __attribute__((address_space(1))) void*)(srcB[i] + ko),
                                                 (__attribute__((address_space(3))) void*)(db + dcb[i]), 16, 0, 0);
            if constexpr (NTB == 2) asm volatile("s_waitcnt vmcnt(8)" ::: "memory");
            else                    asm volatile("s_waitcnt vmcnt(6)" ::: "memory");
        } else if (t + 2 == NT) {
            if constexpr (NTB == 2) asm volatile("s_waitcnt vmcnt(4)" ::: "memory");
            else                    asm volatile("s_waitcnt vmcnt(3)" ::: "memory");
        } else {
            asm volatile("s_waitcnt vmcnt(0)" ::: "memory");
        }
        __builtin_amdgcn_s_barrier();            // buf[rb] staged on all waves
        asm volatile("" ::: "memory");

        const u8* la = &lA[rb * 16384];
        const u8* lb = &lB[rb * (8192 * NTB)];
        const int cb = hf * 2;
        i32x8 af[4], bf[NTB];
#pragma unroll
        for (int mt = 0; mt < 4; mt++)
            af[mt] = frag64(la, wm * 128 + mt * 32 + r32, cb);
#pragma unroll
        for (int nt = 0; nt < NTB; nt++)
            bf[nt] = frag64(lb, wn * (32 * NTB) + nt * 32 + r32, cb);
        asm volatile("s_waitcnt lgkmcnt(0)" ::: "memory");
        __builtin_amdgcn_sched_barrier(0);
        __builtin_amdgcn_s_setprio(1);
#pragma unroll
        for (int mt = 0; mt < 4; mt++)
#pragma unroll
            for (int nt = 0; nt < NTB; nt++)
                acc[mt][nt] = __builtin_amdgcn_mfma_scale_f32_32x32x64_f8f6f4(
                    af[mt], bf[nt], acc[mt][nt], 0, 0, 0, SCALE_ONE, 0, SCALE_ONE);
        __builtin_amdgcn_s_setprio(0);
        __builtin_amdgcn_s_barrier();            // reads of buf[rb] done
        asm volatile("" ::: "memory");
        rb = rb == 2 ? 0 : rb + 1;
        wb = wb == 2 ? 0 : wb + 1;
    }

    // epilogue: C/D 32x32 layout: col=lane&31, row=(reg&3)+8*(reg>>2)+4*(lane>>5)
#pragma unroll
    for (int nt = 0; nt < NTB; nt++) {
        const int col = (int)n0 + wn * (32 * NTB) + nt * 32 + r32;
        const float bcol = bias[col];
        float s = 0.f, sq = 0.f;
#pragma unroll
        for (int mt = 0; mt < 4; mt++)
#pragma unroll
            for (int r = 0; r < 16; r++) {
                const long row = m0 + wm * 128 + mt * 32 + 4 * hf + (r & 3) + 8 * (r >> 2);
                float v = acc[mt][nt][r] * inv + bcol;
                v = fmaxf(v, 0.f);
                C[row * N + col] = f2fp8(v);
                s += v; sq += v * v;
            }
        s += __shfl_xor(s, 32);
        sq += __shfl_xor(sq, 32);
        if (hf == 0) { atomicAdd(&sums[col], s); atomicAdd(&ssq[col], sq); }
    }
}

// ---------------------------------------------------------------------------
// Kernel 4: fused middle stage.
//  blocks 0..511:   transpose W2 (1024x512) -> w2f with a1[k] scale inline
//  blocks 512..519: b2a[col] = b2[col] + sum_k c1[k]*W2[k,col]
//  block  520:      vv[k] = sum_j W3[k,j]*Wc[j]; c0 = b3.Wc + bc
// ---------------------------------------------------------------------------
__global__ __launch_bounds__(256) void k_mid(const float* __restrict__ sums1,
                                             const float* __restrict__ ssq1,
                                             const float* __restrict__ g1,
                                             const float* __restrict__ beta1,
                                             const float* __restrict__ W2,
                                             const float* __restrict__ b2,
                                             u8* __restrict__ w2f,
                                             float* __restrict__ b2a,
                                             const float* __restrict__ W3,
                                             const float* __restrict__ b3,
                                             const float* __restrict__ Wc,
                                             const float* __restrict__ bc,
                                             float* __restrict__ vv,
                                             float* __restrict__ c0) {
    const int bid = blockIdx.x;
    if (bid < 512) {
        __shared__ float tile[32][33];
        __shared__ float sc[32];
        const int nb = (bid & 15) * 32;          // 16 col-blocks over N=512
        const int kb = (bid >> 4) * 32;          // 32 row-blocks over K=1024
        const int tx = threadIdx.x & 31, ty = threadIdx.x >> 5;
        if (threadIdx.x < 32) {
            const int k = kb + threadIdx.x;
            const float m = sums1[k] * INVB;
            const float var = ssq1[k] * INVB - m * m;
            sc[threadIdx.x] = g1[k] * rsqrtf(var + 1e-5f);
        }
        __syncthreads();
        for (int r = ty; r < 32; r += 8)
            tile[r][tx] = sc[r] * W2[(long)(kb + r) * 512 + nb + tx];
        __syncthreads();
        for (int r = ty; r < 32; r += 8)
            w2f[(long)(nb + r) * 1024 + kb + tx] = f2fp8(WSCALE * tile[tx][r]);
    } else if (bid < 520) {
        __shared__ float c1s[1024];
        __shared__ float part[4][64];
        for (int k = threadIdx.x; k < 1024; k += 256) {
            const float m = sums1[k] * INVB;
            const float var = ssq1[k] * INVB - m * m;
            const float a = g1[k] * rsqrtf(var + 1e-5f);
            c1s[k] = beta1[k] - a * m;
        }
        __syncthreads();
        const int lane = threadIdx.x & 63, w = threadIdx.x >> 6;
        const int col = (bid - 512) * 64 + lane;
        float s = 0.f;
        for (int k = w * 256; k < w * 256 + 256; k++)
            s += c1s[k] * W2[(long)k * 512 + col];
        part[w][lane] = s;
        __syncthreads();
        if (w == 0)
            b2a[col] = b2[col] + part[0][lane] + part[1][lane] + part[2][lane] + part[3][lane];
    } else {
        for (int k = threadIdx.x; k < 512; k += 256) {
            float s = 0.f;
            for (int j = 0; j < 64; j++) s += W3[k * 64 + j] * Wc[j];
            vv[k] = s;
        }
        if (threadIdx.x == 0) {
            float s = 0.f;
            for (int j = 0; j < 64; j++) s += b3[j] * Wc[j];
            *c0 = s + bc[0];
        }
    }
}

// ---------------------------------------------------------------------------
// Kernel 6: out[b] = sum_k (a2[k]*h2[b,k]+c2[k])*v[k] + spair[b] + c0
//           a2/c2 computed inline from BN2 raw stats (bit-identical formulas)
// ---------------------------------------------------------------------------
__global__ __launch_bounds__(256) void k_final(const u8* __restrict__ h2,
                                               const float* __restrict__ sums2,
                                               const float* __restrict__ ssq2,
                                               const float* __restrict__ g2,
                                               const float* __restrict__ beta2,
                                               const float* __restrict__ v,
                                               const float* __restrict__ c0,
                                               const float* __restrict__ spair,
                                               float* __restrict__ out) {
    const int wave = threadIdx.x >> 6, lane = threadIdx.x & 63;
    const long b = (long)blockIdx.x * 4 + wave;
    const int k0 = lane * 8;
    uint2 hv = *(const uint2*)&h2[b * 512 + k0];
    float f[8];
    f[0] = __builtin_amdgcn_cvt_f32_fp8(hv.x, 0);
    f[1] = __builtin_amdgcn_cvt_f32_fp8(hv.x, 1);
    f[2] = __builtin_amdgcn_cvt_f32_fp8(hv.x, 2);
    f[3] = __builtin_amdgcn_cvt_f32_fp8(hv.x, 3);
    f[4] = __builtin_amdgcn_cvt_f32_fp8(hv.y, 0);
    f[5] = __builtin_amdgcn_cvt_f32_fp8(hv.y, 1);
    f[6] = __builtin_amdgcn_cvt_f32_fp8(hv.y, 2);
    f[7] = __builtin_amdgcn_cvt_f32_fp8(hv.y, 3);
    float4 sm0 = *(const float4*)&sums2[k0], sm1 = *(const float4*)&sums2[k0 + 4];
    float4 sq0 = *(const float4*)&ssq2[k0],  sq1 = *(const float4*)&ssq2[k0 + 4];
    float4 gg0 = *(const float4*)&g2[k0],    gg1 = *(const float4*)&g2[k0 + 4];
    float4 bb0 = *(const float4*)&beta2[k0], bb1 = *(const float4*)&beta2[k0 + 4];
    float4 vv0 = *(const float4*)&v[k0],     vv1 = *(const float4*)&v[k0 + 4];
    float sm[8] = {sm0.x, sm0.y, sm0.z, sm0.w, sm1.x, sm1.y, sm1.z, sm1.w};
    float sq[8] = {sq0.x, sq0.y, sq0.z, sq0.w, sq1.x, sq1.y, sq1.z, sq1.w};
    float gg[8] = {gg0.x, gg0.y, gg0.z, gg0.w, gg1.x, gg1.y, gg1.z, gg1.w};
    float bb[8] = {bb0.x, bb0.y, bb0.z, bb0.w, bb1.x, bb1.y, bb1.z, bb1.w};
    float vk[8] = {vv0.x, vv0.y, vv0.z, vv0.w, vv1.x, vv1.y, vv1.z, vv1.w};
    float acc = 0.f;
#pragma unroll
    for (int j = 0; j < 8; j++) {
        const float m = sm[j] * INVB;
        const float var = sq[j] * INVB - m * m;
        const float a = gg[j] * rsqrtf(var + 1e-5f);
        const float c = bb[j] - a * m;
        acc += (a * f[j] + c) * vk[j];
    }
    for (int off = 1; off < 64; off <<= 1) acc += __shfl_xor(acc, off);
    if (lane == 0) out[b] = acc + spair[b] + c0[0];
}

// ---------------------------------------------------------------------------
extern "C" void kernel_launch(void* const* d_in, const int* in_sizes, int n_in,
                              void* d_out, int out_size, void* d_ws, size_t ws_size,
                              hipStream_t stream) {
    const float* x     = (const float*)d_in[0];
    const float* W1    = (const float*)d_in[1];
    const float* b1    = (const float*)d_in[2];
    const float* g1    = (const float*)d_in[3];
    const float* beta1 = (const float*)d_in[4];
    const float* W2    = (const float*)d_in[5];
    const float* b2    = (const float*)d_in[6];
    const float* g2    = (const float*)d_in[7];
    const float* beta2 = (const float*)d_in[8];
    const float* W3    = (const float*)d_in[9];
    const float* b3    = (const float*)d_in[10];
    const float* Wc    = (const float*)d_in[11];
    const float* bc    = (const float*)d_in[12];
    float* out = (float*)d_out;

    char* ws = (char*)d_ws;
    size_t o = 0;
    u8* xb  = (u8*)(ws + o); o += BATCH * 2048;             // 33.6 MB fp8
    u8* w1f = (u8*)(ws + o); o += 2048L * 1024;             //  2.1 MB
    u8* w2f = (u8*)(ws + o); o += 1024L * 512;              //  0.5 MB
    u8* h1b = (u8*)(ws + o); o += BATCH * 1024;             // 16.8 MB (raw relu1, fp8)
    u8* h2b = (u8*)(ws + o); o += BATCH * 512;              //  8.4 MB (raw relu2, fp8)
    float* spair = (float*)(ws + o); o += BATCH * 4;
    float* stats = (float*)(ws + o); o += 3072 * 4;
    float* sums1 = stats, *ssq1 = stats + 1024, *sums2 = stats + 2048, *ssq2 = stats + 2560;
    float* vv = (float*)(ws + o); o += 512 * 4;
    float* c0 = (float*)(ws + o); o += 4;
    float* b2a = (float*)(ws + o); o += 512 * 4;

    // gram + x->fp8 + stats-zero (blocks 0..4095) and W1 transpose (4096..6143)
    k_gram<<<6144, 256, 0, stream>>>(x, Wc, W1, xb, w1f, spair, stats);
    // GEMM1: 256x256 tile, BK=64, triple-buffered counted-vmcnt pipeline
    gemm_pipe<2><<<256, 512, 0, stream>>>(xb, w1f, b1, h1b, sums1, ssq1, 1024, 2048, INV_WSCALE);
    // BN1 fold + W2 transpose + b2 adjust + head fold (one dispatch)
    k_mid<<<521, 256, 0, stream>>>(sums1, ssq1, g1, beta1, W2, b2, w2f, b2a,
                                   W3, b3, Wc, bc, vv, c0);
    // GEMM2: 256x128 tile, same pipeline
    gemm_pipe<1><<<256, 512, 0, stream>>>(h1b, w2f, b2a, h2b, sums2, ssq2, 512, 1024, INV_WSCALE);
    // final: BN2 stats inline + head reduction
    k_final<<<4096, 256, 0, stream>>>(h2b, sums2, ssq2, g2, beta2, vv, c0, spair, out);
}

// Round 4
// 299.398 us; speedup vs baseline: 1.0223x; 1.0223x over previous
//
#include <hip/hip_runtime.h>
#include <stdint.h>

typedef unsigned short u16;
typedef unsigned char u8;
typedef __attribute__((ext_vector_type(8))) short short8;
typedef __attribute__((ext_vector_type(4))) float f32x4;
typedef __attribute__((ext_vector_type(16))) float f32x16;
typedef __attribute__((ext_vector_type(4))) int i32x4;
typedef __attribute__((ext_vector_type(8))) int i32x8;

#define BATCH 16384L
#define WSCALE 64.0f
#define INV_WSCALE (1.0f / 64.0f)
#define SCALE_ONE 0x7f7f7f7f   // e8m0 biased exp 127 = 1.0 in all 4 bytes
#define INVB (1.0f / 16384.0f)

__device__ __forceinline__ u16 f2bf_trunc(float f) {
    union { float f; uint32_t u; } cv; cv.f = f;
    return (u16)(cv.u >> 16);
}
__device__ __forceinline__ float bf2f(u16 h) {
    union { uint32_t u; float f; } cv; cv.u = ((uint32_t)h) << 16;
    return cv.f;
}
template<bool HI>
__device__ __forceinline__ uint32_t fp8pk(float a, float b, uint32_t old) {
    return (uint32_t)__builtin_amdgcn_cvt_pk_fp8_f32(a, b, (int)old, HI);
}
__device__ __forceinline__ u8 f2fp8(float v) {
    return (u8)(__builtin_amdgcn_cvt_pk_fp8_f32(v, v, 0, false) & 0xff);
}

// ---------------------------------------------------------------------------
// Kernel 1: per-batch gram pairs (truncating hi/lo split bf16 MFMA ~ fp32)
//           + emit fp8 copy of x for GEMM1 (reads x exactly once)
//           + block 0 zeroes the BN-stats accumulators (replaces memset)
//           + blocks >= 4096: W1 fp32->fp8 transpose
// Note: the (mt=1,nt=0) gram quadrant (rows 16-31 x cols 0-15) never hits the
// upper triangle (col>row impossible) -> its 3 MFMAs + fold are skipped.
// ---------------------------------------------------------------------------
__global__ __launch_bounds__(256) void k_gram(const float* __restrict__ x,
                                              const float* __restrict__ Wc,
                                              const float* __restrict__ W1,
                                              u8* __restrict__ xb,
                                              u8* __restrict__ w1f,
                                              float* __restrict__ spair,
                                              float* __restrict__ stats) {
    if (blockIdx.x >= 4096) {
        // W1 (2048x1024) -> w1f (1024x2048) fp8, scale 64
        __shared__ float tile[32][33];
        const int bid2 = blockIdx.x - 4096;           // 0..2047
        const int nb = (bid2 & 31) * 32;              // over N=1024
        const int kb = (bid2 >> 5) * 32;              // over K=2048
        const int tx = threadIdx.x & 31, ty = threadIdx.x >> 5;
        for (int r = ty; r < 32; r += 8)
            tile[r][tx] = W1[(long)(kb + r) * 1024 + nb + tx];
        __syncthreads();
        for (int r = ty; r < 32; r += 8)
            w1f[(long)(nb + r) * 2048 + kb + tx] = f2fp8(WSCALE * tile[tx][r]);
        return;
    }
    if (blockIdx.x == 0) {
        for (int j = threadIdx.x; j < 3072; j += 256) stats[j] = 0.f;
    }
    const int wave = threadIdx.x >> 6;
    const int lane = threadIdx.x & 63;
    const long b = (long)blockIdx.x * 4 + wave;
    const int r16 = lane & 15, quad = lane >> 4;
    const float* xg = x + b * 2048;

    short8 hi[2][2], lo[2][2];
    for (int mt = 0; mt < 2; mt++) {
        for (int k0 = 0; k0 < 2; k0++) {
            const int row = mt * 16 + r16;
            const int kof = k0 * 32 + quad * 8;
            const float* p = xg + row * 64 + kof;
            float4 p0 = *(const float4*)p;
            float4 p1 = *(const float4*)(p + 4);
            float v[8] = {p0.x, p0.y, p0.z, p0.w, p1.x, p1.y, p1.z, p1.w};
            short8 h, l;
            for (int j = 0; j < 8; j++) {
                u16 hb = f2bf_trunc(v[j]);          // truncate: lo absorbs the error
                h[j] = (short)hb;
                l[j] = (short)f2bf_trunc(v[j] - bf2f(hb));
            }
            hi[mt][k0] = h; lo[mt][k0] = l;
            uint32_t w0 = fp8pk<false>(v[0], v[1], 0); w0 = fp8pk<true>(v[2], v[3], w0);
            uint32_t w1 = fp8pk<false>(v[4], v[5], 0); w1 = fp8pk<true>(v[6], v[7], w1);
            *(uint2*)(xb + b * 2048 + row * 64 + kof) = make_uint2(w0, w1);
        }
    }
    f32x4 zero = {0.f, 0.f, 0.f, 0.f};
    f32x4 acc[2][2];
    for (int mt = 0; mt < 2; mt++) for (int nt = 0; nt < 2; nt++) acc[mt][nt] = zero;
    for (int k0 = 0; k0 < 2; k0++)
        for (int mt = 0; mt < 2; mt++)
            for (int nt = 0; nt < 2; nt++) {
                if (mt == 1 && nt == 0) continue;   // dead quadrant: col>row impossible
                acc[mt][nt] = __builtin_amdgcn_mfma_f32_16x16x32_bf16(hi[mt][k0], hi[nt][k0], acc[mt][nt], 0, 0, 0);
                acc[mt][nt] = __builtin_amdgcn_mfma_f32_16x16x32_bf16(hi[mt][k0], lo[nt][k0], acc[mt][nt], 0, 0, 0);
                acc[mt][nt] = __builtin_amdgcn_mfma_f32_16x16x32_bf16(lo[mt][k0], hi[nt][k0], acc[mt][nt], 0, 0, 0);
            }
    float pacc = 0.f;
    for (int mt = 0; mt < 2; mt++)
        for (int nt = 0; nt < 2; nt++) {
            if (mt == 1 && nt == 0) continue;
            for (int r = 0; r < 4; r++) {
                int row = mt * 16 + quad * 4 + r;
                int col = nt * 16 + r16;
                if (col > row) {
                    int p = 31 * row - (row * (row - 1)) / 2 + (col - row - 1);
                    pacc += acc[mt][nt][r] * Wc[64 + p];
                }
            }
        }
    for (int off = 1; off < 64; off <<= 1) pacc += __shfl_xor(pacc, off);
    if (lane == 0) spair[b] = pacc;
}

// ---------------------------------------------------------------------------
// 32B fragment from XOR-swizzled LDS row: two independently-indexed 16B chunks
// ---------------------------------------------------------------------------
__device__ __forceinline__ i32x8 frag32(const u8* __restrict__ lds, int R, int cb) {
    const int s = R & 7;
    i32x4 lo = *(const i32x4*)&lds[R * 128 + ((cb ^ s) * 16)];
    i32x4 hi = *(const i32x4*)&lds[R * 128 + (((cb + 1) ^ s) * 16)];
    i32x8 r;
    r[0] = lo[0]; r[1] = lo[1]; r[2] = lo[2]; r[3] = lo[3];
    r[4] = hi[0]; r[5] = hi[1]; r[6] = hi[2]; r[7] = hi[3];
    return r;
}

// ---------------------------------------------------------------------------
// Kernel 3a: 256x256-tile, 4-phase-per-K-tile, double-buffered MX-fp8 GEMM
//            (R2-proven structure).
// ---------------------------------------------------------------------------
template<int LOGNB>
__global__ __launch_bounds__(512) void gemm_bn8(const u8* __restrict__ A,
                                                const u8* __restrict__ Bt,
                                                const float* __restrict__ bias,
                                                u8* __restrict__ C,
                                                float* __restrict__ sums,
                                                float* __restrict__ ssq,
                                                int N, int K, float inv) {
    __shared__ u8 lA[2][32768];
    __shared__ u8 lB[2][32768];
    const int tid = threadIdx.x;
    const int lane = tid & 63, wave = tid >> 6;
    const int wm = wave >> 2, wn = wave & 3;         // 2M x 4N waves
    const int r32 = lane & 31, hf = lane >> 5;
    const int lid = blockIdx.x;
    const int xcd = lid & 7, t = lid >> 3;
    const int nbk = t & ((1 << LOGNB) - 1);
    const int mbk = xcd * (32 >> LOGNB) + (t >> LOGNB);
    const long m0 = (long)mbk * 256;
    const long n0 = (long)nbk * 256;

    const u8* srcA[4]; const u8* srcB[4]; int dstc[4];
#pragma unroll
    for (int i = 0; i < 4; i++) {
        const int c = tid + 512 * i;                 // 0..2047: 256 rows x 8 chunks
        const int row = c >> 3, pos = c & 7;
        const int g = pos ^ (row & 7);
        srcA[i] = A + (m0 + row) * (long)K + g * 16;
        srcB[i] = Bt + (n0 + row) * (long)K + g * 16;
        dstc[i] = c * 16;
    }

    f32x16 acc[4][2];
#pragma unroll
    for (int mt = 0; mt < 4; mt++)
#pragma unroll
        for (int nt = 0; nt < 2; nt++)
#pragma unroll
            for (int r = 0; r < 16; r++) acc[mt][nt][r] = 0.f;

    // prologue: stage K-tile 0 into buffer 0, full drain once
#pragma unroll
    for (int i = 0; i < 4; i++)
        __builtin_amdgcn_global_load_lds((const __attribute__((address_space(1))) void*)srcA[i],
                                         (__attribute__((address_space(3))) void*)(&lA[0][dstc[i]]), 16, 0, 0);
#pragma unroll
    for (int i = 0; i < 4; i++)
        __builtin_amdgcn_global_load_lds((const __attribute__((address_space(1))) void*)srcB[i],
                                         (__attribute__((address_space(3))) void*)(&lB[0][dstc[i]]), 16, 0, 0);
    __syncthreads();

    const int NT = K >> 7;
    for (int ti = 0; ti < NT; ti++) {
        const int cur = ti & 1, nxt = cur ^ 1;
        const long koff = (long)(ti + 1) << 7;
        const bool pf = (ti + 1 < NT);
        const u8* la = &lA[cur][0];
        const u8* lb = &lB[cur][0];
        i32x8 af[4], bf;

        // ---- phase 0: A km0 frags + B km0 nt0 ; issue A prefetch (t+1)
#pragma unroll
        for (int mt = 0; mt < 4; mt++)
            af[mt] = frag32(la, wm * 128 + mt * 32 + r32, hf * 2);
        bf = frag32(lb, wn * 64 + r32, hf * 2);
        if (pf) {
#pragma unroll
            for (int i = 0; i < 4; i++)
                __builtin_amdgcn_global_load_lds((const __attribute__((address_space(1))) void*)(srcA[i] + koff),
                                                 (__attribute__((address_space(3))) void*)(&lA[nxt][dstc[i]]), 16, 0, 0);
        }
        __builtin_amdgcn_s_barrier();
        asm volatile("s_waitcnt lgkmcnt(0)" ::: "memory");
        __builtin_amdgcn_sched_barrier(0);
        __builtin_amdgcn_s_setprio(1);
#pragma unroll
        for (int mt = 0; mt < 4; mt++)
            acc[mt][0] = __builtin_amdgcn_mfma_scale_f32_32x32x64_f8f6f4(
                af[mt], bf, acc[mt][0], 0, 0, 0, SCALE_ONE, 0, SCALE_ONE);
        __builtin_amdgcn_s_setprio(0);
        __builtin_amdgcn_s_barrier();

        // ---- phase 1: B km0 nt1 ; issue B prefetch (t+1)
        bf = frag32(lb, wn * 64 + 32 + r32, hf * 2);
        if (pf) {
#pragma unroll
            for (int i = 0; i < 4; i++)
                __builtin_amdgcn_global_load_lds((const __attribute__((address_space(1))) void*)(srcB[i] + koff),
                                                 (__attribute__((address_space(3))) void*)(&lB[nxt][dstc[i]]), 16, 0, 0);
        }
        __builtin_amdgcn_s_barrier();
        asm volatile("s_waitcnt lgkmcnt(0)" ::: "memory");
        __builtin_amdgcn_sched_barrier(0);
        __builtin_amdgcn_s_setprio(1);
#pragma unroll
        for (int mt = 0; mt < 4; mt++)
            acc[mt][1] = __builtin_amdgcn_mfma_scale_f32_32x32x64_f8f6f4(
                af[mt], bf, acc[mt][1], 0, 0, 0, SCALE_ONE, 0, SCALE_ONE);
        __builtin_amdgcn_s_setprio(0);
        __builtin_amdgcn_s_barrier();

        // ---- phase 2: A km1 frags + B km1 nt0
#pragma unroll
        for (int mt = 0; mt < 4; mt++)
            af[mt] = frag32(la, wm * 128 + mt * 32 + r32, 4 + hf * 2);
        bf = frag32(lb, wn * 64 + r32, 4 + hf * 2);
        __builtin_amdgcn_s_barrier();
        asm volatile("s_waitcnt lgkmcnt(0)" ::: "memory");
        __builtin_amdgcn_sched_barrier(0);
        __builtin_amdgcn_s_setprio(1);
#pragma unroll
        for (int mt = 0; mt < 4; mt++)
            acc[mt][0] = __builtin_amdgcn_mfma_scale_f32_32x32x64_f8f6f4(
                af[mt], bf, acc[mt][0], 0, 0, 0, SCALE_ONE, 0, SCALE_ONE);
        __builtin_amdgcn_s_setprio(0);
        __builtin_amdgcn_s_barrier();

        // ---- phase 3: B km1 nt1 ; end-of-tile drain
        bf = frag32(lb, wn * 64 + 32 + r32, 4 + hf * 2);
        __builtin_amdgcn_s_barrier();
        asm volatile("s_waitcnt lgkmcnt(0)" ::: "memory");
        __builtin_amdgcn_sched_barrier(0);
        __builtin_amdgcn_s_setprio(1);
#pragma unroll
        for (int mt = 0; mt < 4; mt++)
            acc[mt][1] = __builtin_amdgcn_mfma_scale_f32_32x32x64_f8f6f4(
                af[mt], bf, acc[mt][1], 0, 0, 0, SCALE_ONE, 0, SCALE_ONE);
        __builtin_amdgcn_s_setprio(0);
        asm volatile("s_waitcnt vmcnt(0)" ::: "memory");
        __builtin_amdgcn_s_barrier();
    }

    // epilogue: C/D 32x32 layout: col=lane&31, row=(reg&3)+8*(reg>>2)+4*(lane>>5)
#pragma unroll
    for (int nt = 0; nt < 2; nt++) {
        const int col = (int)n0 + wn * 64 + nt * 32 + r32;
        const float bcol = bias[col];
        float s = 0.f, sq = 0.f;
#pragma unroll
        for (int mt = 0; mt < 4; mt++)
#pragma unroll
            for (int r = 0; r < 16; r++) {
                const long row = m0 + wm * 128 + mt * 32 + 4 * hf + (r & 3) + 8 * (r >> 2);
                float v = acc[mt][nt][r] * inv + bcol;
                v = fmaxf(v, 0.f);
                C[row * N + col] = f2fp8(v);
                s += v; sq += v * v;
            }
        s += __shfl_xor(s, 32);
        sq += __shfl_xor(sq, 32);
        if (hf == 0) { atomicAdd(&sums[col], s); atomicAdd(&ssq[col], sq); }
    }
}

// ---------------------------------------------------------------------------
// Kernel 3b: 128x128-tile MX-fp8 GEMM (GEMM2, N=512: 512 blocks, 2/CU).
// ---------------------------------------------------------------------------
template<int LOGNB>
__global__ __launch_bounds__(256) void gemm_bn(const u8* __restrict__ A,
                                               const u8* __restrict__ Bt,
                                               const float* __restrict__ bias,
                                               u8* __restrict__ C,
                                               float* __restrict__ sums,
                                               float* __restrict__ ssq,
                                               int N, int K, float inv) {
    __shared__ u8 lA[128 * 128];
    __shared__ u8 lB[128 * 128];
    const int tid = threadIdx.x;
    const int lane = tid & 63, wave = tid >> 6;
    const int wm = wave >> 1, wn = wave & 1;
    const int r32 = lane & 31, hf = lane >> 5;
    const int lid = blockIdx.x;
    const int xcd = lid & 7, t = lid >> 3;
    const int nbk = t & ((1 << LOGNB) - 1);
    const int mbk = (xcd << 4) + (t >> LOGNB);   // 16 bands per XCD
    const long m0 = (long)mbk * 128;
    const long n0 = (long)nbk * 128;

    f32x16 acc[2][2];
    for (int mt = 0; mt < 2; mt++)
        for (int nt = 0; nt < 2; nt++)
            for (int r = 0; r < 16; r++) acc[mt][nt][r] = 0.f;

    for (long k0 = 0; k0 < K; k0 += 128) {
        __syncthreads();
        for (int i = 0; i < 4; i++) {
            const int c = tid + 256 * i;            // 0..1023: 128 rows x 8 chunks
            const int row = c >> 3, pos = c & 7;
            const int g = pos ^ (row & 7);          // source global chunk
            const u8* ga = A + (m0 + row) * K + k0 + g * 16;
            const u8* gb = Bt + (n0 + row) * K + k0 + g * 16;
            __builtin_amdgcn_global_load_lds((const __attribute__((address_space(1))) void*)ga,
                                             (__attribute__((address_space(3))) void*)(&lA[c * 16]), 16, 0, 0);
            __builtin_amdgcn_global_load_lds((const __attribute__((address_space(1))) void*)gb,
                                             (__attribute__((address_space(3))) void*)(&lB[c * 16]), 16, 0, 0);
        }
        __syncthreads();
        for (int km = 0; km < 2; km++) {
            const int cb = km * 4 + hf * 2;         // first 16B chunk of this lane's 32B
            i32x8 af[2], bfr[2];
            for (int mt = 0; mt < 2; mt++)
                af[mt] = frag32(lA, wm * 64 + mt * 32 + r32, cb);
            for (int nt = 0; nt < 2; nt++)
                bfr[nt] = frag32(lB, wn * 64 + nt * 32 + r32, cb);
            for (int mt = 0; mt < 2; mt++)
                for (int nt = 0; nt < 2; nt++)
                    acc[mt][nt] = __builtin_amdgcn_mfma_scale_f32_32x32x64_f8f6f4(
                        af[mt], bfr[nt], acc[mt][nt], 0, 0,
                        0, SCALE_ONE, 0, SCALE_ONE);
        }
    }

    for (int nt = 0; nt < 2; nt++) {
        const int col = (int)n0 + wn * 64 + nt * 32 + r32;
        const float bcol = bias[col];
        float s = 0.f, sq = 0.f;
        for (int mt = 0; mt < 2; mt++)
            for (int r = 0; r < 16; r++) {
                const long row = m0 + wm * 64 + mt * 32 + 4 * hf + (r & 3) + 8 * (r >> 2);
                float v = acc[mt][nt][r] * inv + bcol;
                v = fmaxf(v, 0.f);
                C[row * N + col] = f2fp8(v);
                s += v; sq += v * v;
            }
        s += __shfl_xor(s, 32);
        sq += __shfl_xor(sq, 32);
        if (hf == 0) { atomicAdd(&sums[col], s); atomicAdd(&ssq[col], sq); }
    }
}

// ---------------------------------------------------------------------------
// Kernel 4: fused middle stage.
//  blocks 0..511:   transpose W2 (1024x512) -> w2f with a1[k] scale inline
//  blocks 512..519: b2a[col] = b2[col] + sum_k c1[k]*W2[k,col]
//  block  520:      vv[k] = sum_j W3[k,j]*Wc[j]; c0 = b3.Wc + bc
// ---------------------------------------------------------------------------
__global__ __launch_bounds__(256) void k_mid(const float* __restrict__ sums1,
                                             const float* __restrict__ ssq1,
                                             const float* __restrict__ g1,
                                             const float* __restrict__ beta1,
                                             const float* __restrict__ W2,
                                             const float* __restrict__ b2,
                                             u8* __restrict__ w2f,
                                             float* __restrict__ b2a,
                                             const float* __restrict__ W3,
                                             const float* __restrict__ b3,
                                             const float* __restrict__ Wc,
                                             const float* __restrict__ bc,
                                             float* __restrict__ vv,
                                             float* __restrict__ c0) {
    const int bid = blockIdx.x;
    if (bid < 512) {
        __shared__ float tile[32][33];
        __shared__ float sc[32];
        const int nb = (bid & 15) * 32;          // 16 col-blocks over N=512
        const int kb = (bid >> 4) * 32;          // 32 row-blocks over K=1024
        const int tx = threadIdx.x & 31, ty = threadIdx.x >> 5;
        if (threadIdx.x < 32) {
            const int k = kb + threadIdx.x;
            const float m = sums1[k] * INVB;
            const float var = ssq1[k] * INVB - m * m;
            sc[threadIdx.x] = g1[k] * rsqrtf(var + 1e-5f);
        }
        __syncthreads();
        for (int r = ty; r < 32; r += 8)
            tile[r][tx] = sc[r] * W2[(long)(kb + r) * 512 + nb + tx];
        __syncthreads();
        for (int r = ty; r < 32; r += 8)
            w2f[(long)(nb + r) * 1024 + kb + tx] = f2fp8(WSCALE * tile[tx][r]);
    } else if (bid < 520) {
        __shared__ float c1s[1024];
        __shared__ float part[4][64];
        for (int k = threadIdx.x; k < 1024; k += 256) {
            const float m = sums1[k] * INVB;
            const float var = ssq1[k] * INVB - m * m;
            const float a = g1[k] * rsqrtf(var + 1e-5f);
            c1s[k] = beta1[k] - a * m;
        }
        __syncthreads();
        const int lane = threadIdx.x & 63, w = threadIdx.x >> 6;
        const int col = (bid - 512) * 64 + lane;
        float s = 0.f;
        for (int k = w * 256; k < w * 256 + 256; k++)
            s += c1s[k] * W2[(long)k * 512 + col];
        part[w][lane] = s;
        __syncthreads();
        if (w == 0)
            b2a[col] = b2[col] + part[0][lane] + part[1][lane] + part[2][lane] + part[3][lane];
    } else {
        for (int k = threadIdx.x; k < 512; k += 256) {
            float s = 0.f;
            for (int j = 0; j < 64; j++) s += W3[k * 64 + j] * Wc[j];
            vv[k] = s;
        }
        if (threadIdx.x == 0) {
            float s = 0.f;
            for (int j = 0; j < 64; j++) s += b3[j] * Wc[j];
            *c0 = s + bc[0];
        }
    }
}

// ---------------------------------------------------------------------------
// Kernel 6: out[b] = sum_k (a2[k]*h2[b,k]+c2[k])*v[k] + spair[b] + c0
//           a2/c2 computed inline from BN2 raw stats (bit-identical formulas)
// ---------------------------------------------------------------------------
__global__ __launch_bounds__(256) void k_final(const u8* __restrict__ h2,
                                               const float* __restrict__ sums2,
                                               const float* __restrict__ ssq2,
                                               const float* __restrict__ g2,
                                               const float* __restrict__ beta2,
                                               const float* __restrict__ v,
                                               const float* __restrict__ c0,
                                               const float* __restrict__ spair,
                                               float* __restrict__ out) {
    const int wave = threadIdx.x >> 6, lane = threadIdx.x & 63;
    const long b = (long)blockIdx.x * 4 + wave;
    const int k0 = lane * 8;
    uint2 hv = *(const uint2*)&h2[b * 512 + k0];
    float f[8];
    f[0] = __builtin_amdgcn_cvt_f32_fp8(hv.x, 0);
    f[1] = __builtin_amdgcn_cvt_f32_fp8(hv.x, 1);
    f[2] = __builtin_amdgcn_cvt_f32_fp8(hv.x, 2);
    f[3] = __builtin_amdgcn_cvt_f32_fp8(hv.x, 3);
    f[4] = __builtin_amdgcn_cvt_f32_fp8(hv.y, 0);
    f[5] = __builtin_amdgcn_cvt_f32_fp8(hv.y, 1);
    f[6] = __builtin_amdgcn_cvt_f32_fp8(hv.y, 2);
    f[7] = __builtin_amdgcn_cvt_f32_fp8(hv.y, 3);
    float4 sm0 = *(const float4*)&sums2[k0], sm1 = *(const float4*)&sums2[k0 + 4];
    float4 sq0 = *(const float4*)&ssq2[k0],  sq1 = *(const float4*)&ssq2[k0 + 4];
    float4 gg0 = *(const float4*)&g2[k0],    gg1 = *(const float4*)&g2[k0 + 4];
    float4 bb0 = *(const float4*)&beta2[k0], bb1 = *(const float4*)&beta2[k0 + 4];
    float4 vv0 = *(const float4*)&v[k0],     vv1 = *(const float4*)&v[k0 + 4];
    float sm[8] = {sm0.x, sm0.y, sm0.z, sm0.w, sm1.x, sm1.y, sm1.z, sm1.w};
    float sq[8] = {sq0.x, sq0.y, sq0.z, sq0.w, sq1.x, sq1.y, sq1.z, sq1.w};
    float gg[8] = {gg0.x, gg0.y, gg0.z, gg0.w, gg1.x, gg1.y, gg1.z, gg1.w};
    float bb[8] = {bb0.x, bb0.y, bb0.z, bb0.w, bb1.x, bb1.y, bb1.z, bb1.w};
    float vk[8] = {vv0.x, vv0.y, vv0.z, vv0.w, vv1.x, vv1.y, vv1.z, vv1.w};
    float acc = 0.f;
#pragma unroll
    for (int j = 0; j < 8; j++) {
        const float m = sm[j] * INVB;
        const float var = sq[j] * INVB - m * m;
        const float a = gg[j] * rsqrtf(var + 1e-5f);
        const float c = bb[j] - a * m;
        acc += (a * f[j] + c) * vk[j];
    }
    for (int off = 1; off < 64; off <<= 1) acc += __shfl_xor(acc, off);
    if (lane == 0) out[b] = acc + spair[b] + c0[0];
}

// ---------------------------------------------------------------------------
extern "C" void kernel_launch(void* const* d_in, const int* in_sizes, int n_in,
                              void* d_out, int out_size, void* d_ws, size_t ws_size,
                              hipStream_t stream) {
    const float* x     = (const float*)d_in[0];
    const float* W1    = (const float*)d_in[1];
    const float* b1    = (const float*)d_in[2];
    const float* g1    = (const float*)d_in[3];
    const float* beta1 = (const float*)d_in[4];
    const float* W2    = (const float*)d_in[5];
    const float* b2    = (const float*)d_in[6];
    const float* g2    = (const float*)d_in[7];
    const float* beta2 = (const float*)d_in[8];
    const float* W3    = (const float*)d_in[9];
    const float* b3    = (const float*)d_in[10];
    const float* Wc    = (const float*)d_in[11];
    const float* bc    = (const float*)d_in[12];
    float* out = (float*)d_out;

    char* ws = (char*)d_ws;
    size_t o = 0;
    u8* xb  = (u8*)(ws + o); o += BATCH * 2048;             // 33.6 MB fp8
    u8* w1f = (u8*)(ws + o); o += 2048L * 1024;             //  2.1 MB
    u8* w2f = (u8*)(ws + o); o += 1024L * 512;              //  0.5 MB
    u8* h1b = (u8*)(ws + o); o += BATCH * 1024;             // 16.8 MB (raw relu1, fp8)
    u8* h2b = (u8*)(ws + o); o += BATCH * 512;              //  8.4 MB (raw relu2, fp8)
    float* spair = (float*)(ws + o); o += BATCH * 4;
    float* stats = (float*)(ws + o); o += 3072 * 4;
    float* sums1 = stats, *ssq1 = stats + 1024, *sums2 = stats + 2048, *ssq2 = stats + 2560;
    float* vv = (float*)(ws + o); o += 512 * 4;
    float* c0 = (float*)(ws + o); o += 4;
    float* b2a = (float*)(ws + o); o += 512 * 4;

    // gram + x->fp8 + stats-zero (blocks 0..4095) and W1 transpose (4096..6143)
    k_gram<<<6144, 256, 0, stream>>>(x, Wc, W1, xb, w1f, spair, stats);
    // GEMM1: 256x256-tile 4-phase pipelined (256 blocks, 1/CU, 8 waves)
    gemm_bn8<2><<<256, 512, 0, stream>>>(xb, w1f, b1, h1b, sums1, ssq1, 1024, 2048, INV_WSCALE);
    // BN1 fold + W2 transpose + b2 adjust + head fold (one dispatch)
    k_mid<<<521, 256, 0, stream>>>(sums1, ssq1, g1, beta1, W2, b2, w2f, b2a,
                                   W3, b3, Wc, bc, vv, c0);
    // GEMM2: 128x128 serial structure (R2-proven; 512 blocks, 2/CU)
    gemm_bn<2><<<512, 256, 0, stream>>>(h1b, w2f, b2a, h2b, sums2, ssq2, 512, 1024, INV_WSCALE);
    // final: BN2 stats inline + head reduction
    k_final<<<4096, 256, 0, stream>>>(h2b, sums2, ssq2, g2, beta2, vv, c0, spair, out);
}